// Round 1
// baseline (517.717 us; speedup 1.0000x reference)
//
#include <hip/hip_runtime.h>

// Problem constants (fixed by the reference setup_inputs)
#define BB 4
#define CC 64
#define HH 512
#define WW 512
#define NN 2048
// slots = B * (H/16) * (W/16) = 4 * 32 * 32
#define SLOTS 4096

// d_ws layout: heads[SLOTS], nxt[NN]

// ---- Fused prelude: init heads, detect index dtype, build per-slot lists ----
// Single block of 1024 threads; __syncthreads orders the three phases.
__global__ __launch_bounds__(1024) void prelude_kernel(const int* __restrict__ idx,
                                                       int* __restrict__ heads,
                                                       int* __restrict__ nxt) {
    __shared__ int s_is64;
    const int t = threadIdx.x;
    if (t == 0) s_is64 = 1;   // assume int64 until proven otherwise

    // Phase 1: init heads
    #pragma unroll
    for (int i = t; i < SLOTS; i += 1024) heads[i] = -1;
    __syncthreads();

    // Phase 2: dtype detect. If indices are int64 (little-endian, values < 512),
    // every odd int32 word is zero. If int32, the 3072 odd words hold random
    // index values and cannot all be zero. Benign-race stores of 0.
    for (int i = t; i < 3 * NN / 2; i += 1024) {
        if (idx[2 * i + 1] != 0) s_is64 = 0;
    }
    __syncthreads();

    // Phase 3: build linked lists
    const bool is64 = (s_is64 != 0);
    for (int n = t; n < NN; n += 1024) {
        int b, hi, wi;
        if (is64) {            // int64 indices: stride 2 words, low word
            b  = idx[6 * n + 0];
            hi = idx[6 * n + 2];
            wi = idx[6 * n + 4];
        } else {               // int32 indices
            b  = idx[3 * n + 0];
            hi = idx[3 * n + 1];
            wi = idx[3 * n + 2];
        }
        const int slot = (b << 10) | (hi << 5) | wi;   // b*1024 + hi*32 + wi
        nxt[n] = atomicExch(&heads[slot], n);
    }
}

// One thread per FOUR output float4s (4 consecutive h rows within one slot).
// out = in + sum of covering patches. One heads lookup / chain walk serves
// 4 float4s; each chain step issues 4 independent g4 loads (4x MLP).
__global__ __launch_bounds__(256) void scatter_add_kernel(
    const float4* __restrict__ in4,
    const float4* __restrict__ g4,
    const int* __restrict__ heads,
    const int* __restrict__ nxt,
    float4* __restrict__ out4)
{
    const int t  = blockIdx.x * 256 + threadIdx.x;  // t < B*C*(H/4)*(W/4) = 4,194,304
    const int w4 = t & 127;                         // W/4 = 128
    const int hq = (t >> 7) & 127;                  // h/4 in [0,128)
    const int cb = t >> 14;                         // c + C*b
    const int c  = cb & 63;
    const int b  = cb >> 6;
    const int h0 = hq << 2;                         // first of 4 h rows

    const int base = (cb << 16) | (h0 << 7) | w4;   // float4 index into in/out

    float4 v0 = in4[base];
    float4 v1 = in4[base + 128];
    float4 v2 = in4[base + 256];
    float4 v3 = in4[base + 384];

    const int slot = (b << 10) | ((hq >> 2) << 5) | (w4 >> 2);
    int n = heads[slot];
    if (n >= 0) {
        // gathered float4 index: n*4096 + c*64 + (h%16)*4 + (w4%4); rows +4 each
        const int goff = (c << 6) | ((h0 & 15) << 2) | (w4 & 3);
        do {
            const float4* __restrict__ gp = g4 + ((n << 12) + goff);
            const float4 g0 = gp[0];
            const float4 g1 = gp[4];
            const float4 g2 = gp[8];
            const float4 g3 = gp[12];
            const int nn = nxt[n];
            v0.x += g0.x; v0.y += g0.y; v0.z += g0.z; v0.w += g0.w;
            v1.x += g1.x; v1.y += g1.y; v1.z += g1.z; v1.w += g1.w;
            v2.x += g2.x; v2.y += g2.y; v2.z += g2.z; v2.w += g2.w;
            v3.x += g3.x; v3.y += g3.y; v3.z += g3.z; v3.w += g3.w;
            n = nn;
        } while (n >= 0);
    }

    out4[base]       = v0;
    out4[base + 128] = v1;
    out4[base + 256] = v2;
    out4[base + 384] = v3;
}

// ---- Fallback path (only if d_ws is impossibly small): copy + atomic scatter ----
__global__ __launch_bounds__(256) void copy_kernel(const float4* __restrict__ in4,
                                                   float4* __restrict__ out4) {
    int e = blockIdx.x * 256 + threadIdx.x;
    out4[e] = in4[e];
}

__global__ __launch_bounds__(256) void atomic_scatter_kernel(
    const float* __restrict__ g,
    const int* __restrict__ idx,
    float* __restrict__ out)
{
    int i = blockIdx.x * 256 + threadIdx.x;      // i < N*C*16*16 = 33,554,432
    int n = i >> 14;                             // / 16384
    int r = i & 16383;
    int c  = r >> 8;
    int rr = (r >> 4) & 15;
    int w  = r & 15;
    int b  = idx[3 * n + 0];
    int hi = idx[3 * n + 1];
    int wi = idx[3 * n + 2];
    int off = ((b * CC + c) * HH + hi * 16 + rr) * WW + wi * 16 + w;
    atomicAdd(&out[off], g[i]);
}

extern "C" void kernel_launch(void* const* d_in, const int* in_sizes, int n_in,
                              void* d_out, int out_size, void* d_ws, size_t ws_size,
                              hipStream_t stream) {
    const float* inp      = (const float*)d_in[0];
    const float* gathered = (const float*)d_in[1];
    const int*   idx      = (const int*)d_in[2];
    float* out = (float*)d_out;

    const size_t ws_needed = (size_t)(SLOTS + NN) * sizeof(int);

    if (ws_size >= ws_needed) {
        int* heads = (int*)d_ws;
        int* nxt   = heads + SLOTS;
        prelude_kernel<<<1, 1024, 0, stream>>>(idx, heads, nxt);
        const int n_thr = BB * CC * (HH / 4) * (WW / 4);   // 4,194,304
        scatter_add_kernel<<<n_thr / 256, 256, 0, stream>>>(
            (const float4*)inp, (const float4*)gathered, heads, nxt, (float4*)out);
    } else {
        const int n_out4 = BB * CC * HH * (WW / 4);
        copy_kernel<<<n_out4 / 256, 256, 0, stream>>>((const float4*)inp, (float4*)out);
        const int n_g = NN * CC * 16 * 16;                 // 33,554,432
        atomic_scatter_kernel<<<n_g / 256, 256, 0, stream>>>(gathered, idx, out);
    }
}

// Round 4
// 500.813 us; speedup vs baseline: 1.0338x; 1.0338x over previous
//
#include <hip/hip_runtime.h>

// Problem constants (fixed by the reference setup_inputs)
#define BB 4
#define CC 64
#define HH 512
#define WW 512
#define NN 2048
// slots = B * (H/16) * (W/16) = 4 * 32 * 32
#define SLOTS 4096
#define CAP 16          // bucket capacity per slot (P(overflow) ~ 1e-18 for Poisson(0.5))

// Native clang vector type: required by __builtin_nontemporal_load/store
// (HIP's float4 is a class and is rejected).
typedef float vf4 __attribute__((ext_vector_type(4)));

// d_ws layout (ints): lst[SLOTS*CAP], cnts[SLOTS], heads[SLOTS], nxt[NN]

// ---- Fused prelude: init, detect index dtype, build per-slot buckets ----
// Single block of 1024 threads; __syncthreads orders the phases. Bucket
// counters and overflow-chain heads live in LDS; written to ws at the end.
__global__ __launch_bounds__(1024) void prelude_kernel(const int* __restrict__ idx,
                                                       int* __restrict__ lst,
                                                       int* __restrict__ cnts,
                                                       int* __restrict__ heads,
                                                       int* __restrict__ nxt) {
    __shared__ int s_cnt[SLOTS];
    __shared__ int s_head[SLOTS];
    __shared__ int s_is64;
    const int t = threadIdx.x;
    if (t == 0) s_is64 = 1;   // assume int64 until proven otherwise

    for (int i = t; i < SLOTS; i += 1024) { s_cnt[i] = 0; s_head[i] = -1; }
    __syncthreads();

    // dtype detect: if indices are int64 (little-endian, values < 512), every
    // odd int32 word is zero. int32 indices can't have all odd words zero.
    for (int i = t; i < 3 * NN / 2; i += 1024) {
        if (idx[2 * i + 1] != 0) s_is64 = 0;
    }
    __syncthreads();

    const bool is64 = (s_is64 != 0);
    for (int n = t; n < NN; n += 1024) {
        int b, hi, wi;
        if (is64) {            // int64 indices: stride 2 words, low word
            b  = idx[6 * n + 0];
            hi = idx[6 * n + 2];
            wi = idx[6 * n + 4];
        } else {               // int32 indices
            b  = idx[3 * n + 0];
            hi = idx[3 * n + 1];
            wi = idx[3 * n + 2];
        }
        const int slot = (b << 10) | (hi << 5) | wi;   // b*1024 + hi*32 + wi
        const int pos  = atomicAdd(&s_cnt[slot], 1);
        if (pos < CAP) lst[(slot << 4) + pos] = n;                 // bucket
        else           nxt[n] = atomicExch(&s_head[slot], n);      // overflow chain
    }
    __syncthreads();

    for (int i = t; i < SLOTS; i += 1024) { cnts[i] = s_cnt[i]; heads[i] = s_head[i]; }
}

// One thread per FOUR output float4s (4 consecutive h rows within one slot).
// out = in + sum of covering patches. Bucket list replaces the pointer chase:
// patch ids come from an L1-hot 64 KB table, so all gathered loads are
// independent; pair-unrolled loop issues 8 float4 loads per iteration.
__global__ __launch_bounds__(256) void scatter_add_kernel(
    const vf4* __restrict__ in4,
    const vf4* __restrict__ g4,
    const int* __restrict__ lst,
    const int* __restrict__ cnts,
    const int* __restrict__ heads,
    const int* __restrict__ nxt,
    vf4* __restrict__ out4)
{
    const int t  = blockIdx.x * 256 + threadIdx.x;  // t < B*C*(H/4)*(W/4) = 4,194,304
    const int w4 = t & 127;                         // W/4 = 128
    const int hq = (t >> 7) & 127;                  // h/4 in [0,128)
    const int cb = t >> 14;                         // c + C*b
    const int c  = cb & 63;
    const int b  = cb >> 6;
    const int h0 = hq << 2;                         // first of 4 h rows

    const int slot = (b << 10) | ((hq >> 2) << 5) | (w4 >> 2);
    const int cnt  = cnts[slot];                    // L1-hot 16 KB table

    const int base = (cb << 16) | (h0 << 7) | w4;   // float4 index into in/out

    vf4 v0 = __builtin_nontemporal_load(&in4[base]);
    vf4 v1 = __builtin_nontemporal_load(&in4[base + 128]);
    vf4 v2 = __builtin_nontemporal_load(&in4[base + 256]);
    vf4 v3 = __builtin_nontemporal_load(&in4[base + 384]);

    if (cnt > 0) {
        // gathered float4 index: n*4096 + c*64 + (h%16)*4 + (w4%4); rows +4 each
        const int goff  = (c << 6) | ((h0 & 15) << 2) | (w4 & 3);
        const int lbase = slot << 4;
        const int cnt16 = cnt < CAP ? cnt : CAP;
        int i = 0;
        for (; i + 2 <= cnt16; i += 2) {            // pairs: 8 independent loads
            const int n0 = lst[lbase + i];
            const int n1 = lst[lbase + i + 1];
            const vf4* __restrict__ gp0 = g4 + ((n0 << 12) + goff);
            const vf4* __restrict__ gp1 = g4 + ((n1 << 12) + goff);
            const vf4 a0 = __builtin_nontemporal_load(gp0 + 0);
            const vf4 a1 = __builtin_nontemporal_load(gp0 + 4);
            const vf4 a2 = __builtin_nontemporal_load(gp0 + 8);
            const vf4 a3 = __builtin_nontemporal_load(gp0 + 12);
            const vf4 b0 = __builtin_nontemporal_load(gp1 + 0);
            const vf4 b1 = __builtin_nontemporal_load(gp1 + 4);
            const vf4 b2 = __builtin_nontemporal_load(gp1 + 8);
            const vf4 b3 = __builtin_nontemporal_load(gp1 + 12);
            v0 += a0 + b0;
            v1 += a1 + b1;
            v2 += a2 + b2;
            v3 += a3 + b3;
        }
        if (i < cnt16) {                            // odd tail (cnt==1 is 77% of covered)
            const int n0 = lst[lbase + i];
            const vf4* __restrict__ gp0 = g4 + ((n0 << 12) + goff);
            v0 += __builtin_nontemporal_load(gp0 + 0);
            v1 += __builtin_nontemporal_load(gp0 + 4);
            v2 += __builtin_nontemporal_load(gp0 + 8);
            v3 += __builtin_nontemporal_load(gp0 + 12);
        }
        if (cnt > CAP) {                            // never expected; correctness only
            int n = heads[slot];
            while (n >= 0) {
                const vf4* __restrict__ gp = g4 + ((n << 12) + goff);
                const vf4 a0 = gp[0];
                const vf4 a1 = gp[4];
                const vf4 a2 = gp[8];
                const vf4 a3 = gp[12];
                n = nxt[n];
                v0 += a0;
                v1 += a1;
                v2 += a2;
                v3 += a3;
            }
        }
    }

    __builtin_nontemporal_store(v0, &out4[base]);
    __builtin_nontemporal_store(v1, &out4[base + 128]);
    __builtin_nontemporal_store(v2, &out4[base + 256]);
    __builtin_nontemporal_store(v3, &out4[base + 384]);
}

// ---- Fallback path (only if d_ws is impossibly small): copy + atomic scatter ----
__global__ __launch_bounds__(256) void copy_kernel(const vf4* __restrict__ in4,
                                                   vf4* __restrict__ out4) {
    int e = blockIdx.x * 256 + threadIdx.x;
    out4[e] = in4[e];
}

__global__ __launch_bounds__(256) void atomic_scatter_kernel(
    const float* __restrict__ g,
    const int* __restrict__ idx,
    float* __restrict__ out)
{
    int i = blockIdx.x * 256 + threadIdx.x;      // i < N*C*16*16 = 33,554,432
    int n = i >> 14;                             // / 16384
    int r = i & 16383;
    int c  = r >> 8;
    int rr = (r >> 4) & 15;
    int w  = r & 15;
    int b  = idx[3 * n + 0];
    int hi = idx[3 * n + 1];
    int wi = idx[3 * n + 2];
    int off = ((b * CC + c) * HH + hi * 16 + rr) * WW + wi * 16 + w;
    atomicAdd(&out[off], g[i]);
}

extern "C" void kernel_launch(void* const* d_in, const int* in_sizes, int n_in,
                              void* d_out, int out_size, void* d_ws, size_t ws_size,
                              hipStream_t stream) {
    const float* inp      = (const float*)d_in[0];
    const float* gathered = (const float*)d_in[1];
    const int*   idx      = (const int*)d_in[2];
    float* out = (float*)d_out;

    const size_t ws_needed = (size_t)(SLOTS * CAP + SLOTS + SLOTS + NN) * sizeof(int);

    if (ws_size >= ws_needed) {
        int* lst   = (int*)d_ws;           // 64 B-aligned, SLOTS*CAP ints
        int* cnts  = lst + SLOTS * CAP;
        int* heads = cnts + SLOTS;
        int* nxt   = heads + SLOTS;
        prelude_kernel<<<1, 1024, 0, stream>>>(idx, lst, cnts, heads, nxt);
        const int n_thr = BB * CC * (HH / 4) * (WW / 4);   // 4,194,304
        scatter_add_kernel<<<n_thr / 256, 256, 0, stream>>>(
            (const vf4*)inp, (const vf4*)gathered, lst, cnts, heads, nxt,
            (vf4*)out);
    } else {
        const int n_out4 = BB * CC * HH * (WW / 4);
        copy_kernel<<<n_out4 / 256, 256, 0, stream>>>((const vf4*)inp, (vf4*)out);
        const int n_g = NN * CC * 16 * 16;                 // 33,554,432
        atomic_scatter_kernel<<<n_g / 256, 256, 0, stream>>>(gathered, idx, out);
    }
}